// Round 8
// baseline (551.529 us; speedup 1.0000x reference)
//
#include <hip/hip_runtime.h>
#include <math.h>

#define Bn 16
#define Sn 512
#define Hn 768
#define NHn 12
#define DHn 64
#define In 3072
#define TOK (Bn*Sn)

typedef unsigned short u16;
typedef short bf16x8 __attribute__((ext_vector_type(8)));
typedef short bf16x4 __attribute__((ext_vector_type(4)));
typedef float f32x4 __attribute__((ext_vector_type(4)));

__device__ __forceinline__ u16 f2bf(float x) {
    union { float f; unsigned u; } v; v.f = x;
    unsigned r = v.u + 0x7FFF + ((v.u >> 16) & 1);
    return (u16)(r >> 16);
}
__device__ __forceinline__ float bf2f(u16 u) {
    union { unsigned u; float f; } v; v.u = ((unsigned)u) << 16; return v.f;
}

// async global->LDS DMA, 16 B/lane; dest = wave-uniform base + lane*16
__device__ __forceinline__ void gl_lds16(const void* g, void* s) {
    __builtin_amdgcn_global_load_lds((const __attribute__((address_space(1))) void*)g,
                                     (__attribute__((address_space(3))) void*)s, 16, 0, 0);
}

// ---------------- elementwise f32 -> bf16 ----------------
__global__ __launch_bounds__(256) void k_cvt(const float* __restrict__ in, u16* __restrict__ out, int n) {
    int i = (blockIdx.x * 256 + threadIdx.x) * 8;
    if (i + 8 > n) return;
    float4 a = *(const float4*)(in + i);
    float4 b = *(const float4*)(in + i + 4);
    bf16x8 o;
    o[0] = (short)f2bf(a.x); o[1] = (short)f2bf(a.y); o[2] = (short)f2bf(a.z); o[3] = (short)f2bf(a.w);
    o[4] = (short)f2bf(b.x); o[5] = (short)f2bf(b.y); o[6] = (short)f2bf(b.z); o[7] = (short)f2bf(b.w);
    *(bf16x8*)(out + i) = o;
}

// ---------------- fused weight transposes: f32[K,N] -> bf16[N,K], 8 jobs ----------------
struct TJobs {
    const float* src[8];
    u16* dst[8];
    int K[8];
    int N[8];
    int bstart[9];
};

__global__ __launch_bounds__(256) void k_transpose_all(TJobs J) {
    __shared__ float tile[32][33];
    int bid = blockIdx.x;
    int ji = 0;
    #pragma unroll
    for (int t = 0; t < 8; t++) if (bid >= J.bstart[t + 1]) ji = t + 1;
    const float* W = J.src[ji];
    u16* Wt = J.dst[ji];
    int K = J.K[ji], N = J.N[ji];
    int local = bid - J.bstart[ji];
    int nbx = N >> 5;
    int bx = local % nbx, by = local / nbx;
    int n0 = bx * 32, k0 = by * 32;
    int tx = threadIdx.x, ty = threadIdx.y;  // (32,8)
    #pragma unroll
    for (int i = 0; i < 32; i += 8)
        tile[ty + i][tx] = W[(size_t)(k0 + ty + i) * N + n0 + tx];
    __syncthreads();
    #pragma unroll
    for (int i = 0; i < 32; i += 8)
        Wt[(size_t)(n0 + ty + i) * K + k0 + tx] = f2bf(tile[tx][ty + i]);
}

__global__ __launch_bounds__(256) void k_pack_bias(const float* __restrict__ bq, const float* __restrict__ bk,
                                                   const float* __restrict__ bv, float* __restrict__ bqkv) {
    int i = blockIdx.x * 256 + threadIdx.x;
    if (i < 2304) bqkv[i] = (i < 768) ? bq[i] : (i < 1536 ? bk[i - 768] : bv[i - 1536]);
}

// ---------------- bf16 MFMA GEMM: BK=64, global_load_lds, XOR swizzle, XCD-affinity remap ----------------
#define GM_BF16 0
#define GM_F32 1
#define GM_GELU_BF16 2
#define GM_POSH 3   // write bf16 to [h][r][d]: h=col>>6, d=col&63, idx=h*65536+row*64+d

template<int NT>
__global__ __launch_bounds__(256) void k_gemm_t(const u16* __restrict__ A, const u16* __restrict__ Bt,
                                                const float* __restrict__ bias, void* __restrict__ Cout,
                                                int M, int N, int K, int mode) {
    constexpr int TN = NT / 32;
    __shared__ __align__(16) u16 sA[128 * 64];
    __shared__ __align__(16) u16 sB[NT * 64];
    int tid = threadIdx.x;
    int wave = tid >> 6, lane = tid & 63;
    int lane16 = lane & 15, quad = lane >> 4;

    int nb = gridDim.x;
    int flat = blockIdx.y * nb + blockIdx.x;
    int c = flat & 7, g = flat >> 3;
    int mt = c + 8 * (g / nb), nt = g % nb;   // requires gridDim.y % 8 == 0
    int m0 = mt * 128, n0 = nt * NT;

    int wm = (wave >> 1) * 64;
    int wn = (wave & 1) * (NT / 2);
    f32x4 acc[4][TN] = {};

    int r_st = lane >> 3;
    int c8p = lane & 7;

    for (int k0 = 0; k0 < K; k0 += 64) {
        __syncthreads();
        #pragma unroll
        for (int I = 0; I < 4; I++) {
            int Ii = wave + I * 4;
            int r = Ii * 8 + r_st;
            int c8 = c8p ^ (r & 7);
            gl_lds16(&A[(size_t)(m0 + r) * K + k0 + c8 * 8], &sA[Ii * 512]);
        }
        #pragma unroll
        for (int I = 0; I < NT / 32; I++) {
            int Ii = wave + I * 4;
            int r = Ii * 8 + r_st;
            int c8 = c8p ^ (r & 7);
            gl_lds16(&Bt[(size_t)(n0 + r) * K + k0 + c8 * 8], &sB[Ii * 512]);
        }
        __syncthreads();
        #pragma unroll
        for (int h = 0; h < 2; h++) {
            bf16x8 af[4], bfr[TN];
            #pragma unroll
            for (int t = 0; t < 4; t++) {
                int R = wm + t * 16 + lane16;
                af[t] = *(const bf16x8*)&sA[R * 64 + (((4 * h + quad) ^ (R & 7)) << 3)];
            }
            #pragma unroll
            for (int t = 0; t < TN; t++) {
                int R = wn + t * 16 + lane16;
                bfr[t] = *(const bf16x8*)&sB[R * 64 + (((4 * h + quad) ^ (R & 7)) << 3)];
            }
            #pragma unroll
            for (int tm = 0; tm < 4; tm++)
                #pragma unroll
                for (int tn = 0; tn < TN; tn++)
                    acc[tm][tn] = __builtin_amdgcn_mfma_f32_16x16x32_bf16(af[tm], bfr[tn], acc[tm][tn], 0, 0, 0);
        }
    }

    float* Cf = (float*)Cout;
    u16* Ch = (u16*)Cout;
    #pragma unroll
    for (int tm = 0; tm < 4; tm++) {
        #pragma unroll
        for (int tn = 0; tn < TN; tn++) {
            int col = n0 + wn + tn * 16 + lane16;
            float bv_ = bias ? bias[col] : 0.f;
            #pragma unroll
            for (int r = 0; r < 4; r++) {
                int row = m0 + wm + tm * 16 + quad * 4 + r;
                float v = acc[tm][tn][r] + bv_;
                if (mode == GM_GELU_BF16) {
                    v = 0.5f * v * (1.f + erff(v * 0.70710678118654752f));
                    Ch[(size_t)row * N + col] = f2bf(v);
                } else if (mode == GM_BF16) {
                    Ch[(size_t)row * N + col] = f2bf(v);
                } else if (mode == GM_POSH) {
                    Ch[(((size_t)col >> 6) << 16) + ((size_t)row << 6) + (col & 63)] = f2bf(v);
                } else {
                    Cf[(size_t)row * N + col] = v;
                }
            }
        }
    }
}

// ---------------- V transpose: qkv[tok, 1536+h*64+d] -> Vt[(b,h), d, j] ----------------
__global__ __launch_bounds__(256) void k_vt(const u16* __restrict__ qkv, u16* __restrict__ Vt) {
    __shared__ u16 s[64][72];
    int z = blockIdx.y;  // b*12+h
    int j0 = blockIdx.x * 64;
    int b = z / NHn, h = z % NHn;
    int t = threadIdx.x;
    for (int e = t; e < 4096; e += 256) {
        int j = e >> 6, d = e & 63;
        s[j][d] = qkv[(size_t)(b * Sn + j0 + j) * 2304 + 1536 + h * 64 + d];
    }
    __syncthreads();
    for (int e = t; e < 4096; e += 256) {
        int d = e >> 6, jj = e & 63;
        Vt[((size_t)z * 64 + d) * Sn + j0 + jj] = s[jj][d];
    }
}

// ---------------- fused disentangled attention, XCD-affinity z-remap + hoisted DMA ----------------
// flat = y*8+x; xcd=flat&7; g=flat>>3; z = xcd*24 + g%24; i0 = (g/24)*64
// -> all 8 i-tiles of one z share an XCD L2 (K/V panel fetched once per XCD).
// LDS (u16 idx): sK [0,4096) (Q stage at start, P surface later), sV [4096,8192),
// sPK [8192,16384), sPQ [16384,24576); scatter alias s1 [8192,16896), s2 [16896,25600).
__global__ __launch_bounds__(256, 3) void k_attn(const u16* __restrict__ qkv, const u16* __restrict__ poskR,
                                                 const u16* __restrict__ posqR, const u16* __restrict__ Vt,
                                                 const float* __restrict__ mask, u16* __restrict__ ctx) {
    __shared__ __align__(16) u16 smem[25600];
    u16* sK = smem;
    u16* sV = smem + 4096;
    u16* sPK = smem + 8192;
    u16* s1 = smem + 8192;
    u16* s2 = smem + 16896;

    int flat = blockIdx.y * gridDim.x + blockIdx.x;   // grid (8,192)
    int xcd = flat & 7, g = flat >> 3;                // g in [0,192)
    int z = xcd * 24 + (g % 24);
    int i0 = (g / 24) * 64;
    int b = z / NHn, h = z % NHn;
    int tid = threadIdx.x, wave = tid >> 6, lane = tid & 63;
    int lane16 = lane & 15, quad = lane >> 4;
    int lr = lane >> 3, lc8 = lane & 7;
    int c8v = (lc8 ^ lr) << 3;   // lane-const swizzled chunk offset (r&7 == lr for all chunks)

    // ---- stage Q once (into sK), read A-fragments ----
    #pragma unroll
    for (int I = 0; I < 2; I++) {
        int CI = wave * 2 + I;
        int r = CI * 8 + lr;
        gl_lds16(&qkv[(size_t)(b * Sn + i0 + r) * 2304 + h * 64 + c8v], &sK[CI * 512]);
    }
    __syncthreads();
    int Rq = wave * 16 + lane16;
    bf16x8 aq0 = *(const bf16x8*)&sK[Rq * 64 + (((quad    ) ^ (Rq & 7)) << 3)];
    bf16x8 aq1 = *(const bf16x8*)&sK[Rq * 64 + (((quad + 4) ^ (Rq & 7)) << 3)];

    // ---- hoisted staging pointers ----
    const u16* kp0 = qkv + (size_t)(b * Sn + wave * 8 + lr) * 2304 + 768 + h * 64 + c8v;
    const u16* kp1 = qkv + (size_t)(b * Sn + (4 + wave) * 8 + lr) * 2304 + 768 + h * 64 + c8v;
    const u16* vp0 = Vt + ((size_t)z * 64 + wave * 8 + lr) * Sn + c8v;
    const u16* vp1 = Vt + ((size_t)z * 64 + (4 + wave) * 8 + lr) * Sn + c8v;
    const u16* pkb = poskR + (size_t)h * 65536 + c8v;
    const u16* pqb = posqR + (size_t)h * 65536 + c8v;
    int rl0 = wave * 8 + lr;   // pos row lane-term for chunk group q: rl0 + 32q

    f32x4 o[4] = {};
    float m_[4] = {-1e30f, -1e30f, -1e30f, -1e30f};
    float l_[4] = {};
    const float scale = 0.07216878364870323f;  // 1/sqrt(3*64)

    for (int jt = 0; jt < 8; jt++) {
        int j0 = jt * 64;
        int r0pk = i0 - j0 + 449, r0pq = j0 - i0 + 449;
        __syncthreads();  // prior iter's P/sV/s1/s2 uses complete before restage
        // ---- stage K(8) V(8) PK(16) PQ(16) 1KB-chunks, 12 DMA per wave ----
        gl_lds16(kp0, &smem[(wave    ) * 512]);  kp0 += 64 * 2304;
        gl_lds16(kp1, &smem[(4 + wave) * 512]);  kp1 += 64 * 2304;
        gl_lds16(vp0, &smem[(8 + wave) * 512]);  vp0 += 64;
        gl_lds16(vp1, &smem[(12 + wave) * 512]); vp1 += 64;
        #pragma unroll
        for (int q = 0; q < 4; q++) {
            int rl = rl0 + 32 * q;
            int rowk = min(r0pk + rl, 1023);
            int rowq = min(r0pq + rl, 1023);
            gl_lds16(pkb + ((size_t)rowk << 6), &smem[(16 + 4 * q + wave) * 512]);
            gl_lds16(pqb + ((size_t)rowq << 6), &smem[(32 + 4 * q + wave) * 512]);
        }
        float mv[4];
        #pragma unroll
        for (int tn = 0; tn < 4; tn++) mv[tn] = mask[(size_t)b * Sn + j0 + tn * 16 + lane16];
        __syncthreads();  // DMA drain + barrier

        // ---- MFMA phase ----
        bf16x8 ak0 = *(const bf16x8*)&sK[Rq * 64 + (((quad    ) ^ (Rq & 7)) << 3)];
        bf16x8 ak1 = *(const bf16x8*)&sK[Rq * 64 + (((quad + 4) ^ (Rq & 7)) << 3)];
        f32x4 cc[4];
        #pragma unroll
        for (int tn = 0; tn < 4; tn++) {
            int R = tn * 16 + lane16;
            bf16x8 b0 = *(const bf16x8*)&sK[R * 64 + (((quad    ) ^ (R & 7)) << 3)];
            bf16x8 b1 = *(const bf16x8*)&sK[R * 64 + (((quad + 4) ^ (R & 7)) << 3)];
            f32x4 x = {};
            x = __builtin_amdgcn_mfma_f32_16x16x32_bf16(aq0, b0, x, 0, 0, 0);
            x = __builtin_amdgcn_mfma_f32_16x16x32_bf16(aq1, b1, x, 0, 0, 0);
            cc[tn] = x;
        }
        f32x4 a1[8], a2[8];
        #pragma unroll
        for (int tr = 0; tr < 8; tr++) {
            int R = tr * 16 + lane16;
            bf16x8 b0 = *(const bf16x8*)&sPK[R * 64 + (((quad    ) ^ (R & 7)) << 3)];
            bf16x8 b1 = *(const bf16x8*)&sPK[R * 64 + (((quad + 4) ^ (R & 7)) << 3)];
            bf16x8 c0 = *(const bf16x8*)&sPK[8192 + R * 64 + (((quad    ) ^ (R & 7)) << 3)];
            bf16x8 c1 = *(const bf16x8*)&sPK[8192 + R * 64 + (((quad + 4) ^ (R & 7)) << 3)];
            f32x4 x = {}, y = {};
            x = __builtin_amdgcn_mfma_f32_16x16x32_bf16(aq0, b0, x, 0, 0, 0);
            x = __builtin_amdgcn_mfma_f32_16x16x32_bf16(aq1, b1, x, 0, 0, 0);
            y = __builtin_amdgcn_mfma_f32_16x16x32_bf16(ak0, c0, y, 0, 0, 0);
            y = __builtin_amdgcn_mfma_f32_16x16x32_bf16(ak1, c1, y, 0, 0, 0);
            a1[tr] = x; a2[tr] = y;
        }
        __syncthreads();  // pos-window reads done; sPK/sPQ become s1/s2

        // ---- diagonal scatter (bf16, per-wave disjoint columns) ----
        int sw = wave * 16 + quad * 4;
        #pragma unroll
        for (int tr = 0; tr < 8; tr++) {
            bf16x4 oo, pp;
            oo[0] = (short)f2bf(a1[tr][0]); oo[1] = (short)f2bf(a1[tr][1]);
            oo[2] = (short)f2bf(a1[tr][2]); oo[3] = (short)f2bf(a1[tr][3]);
            pp[0] = (short)f2bf(a2[tr][0]); pp[1] = (short)f2bf(a2[tr][1]);
            pp[2] = (short)f2bf(a2[tr][2]); pp[3] = (short)f2bf(a2[tr][3]);
            *(bf16x4*)&s1[(tr * 16 + lane16) * 68 + sw] = oo;
            *(bf16x4*)&s2[(tr * 16 + lane16) * 68 + sw] = pp;
        }
        __syncthreads();

        // ---- gather + online softmax + P write (into dead sK, swizzled) + PV ----
        float S[4][4];
        #pragma unroll
        for (int tn = 0; tn < 4; tn++) {
            int jL = tn * 16 + lane16;
            #pragma unroll
            for (int r = 0; r < 4; r++) {
                int iL = wave * 16 + quad * 4 + r;
                float v = cc[tn][r] + bf2f(s1[(iL - jL + 63) * 68 + iL])
                                    + bf2f(s2[(jL - iL + 63) * 68 + jL]);
                v *= scale;
                S[tn][r] = (mv[tn] > 0.f) ? v : -1e9f;
            }
        }
        #pragma unroll
        for (int r = 0; r < 4; r++) {
            float mx = fmaxf(fmaxf(S[0][r], S[1][r]), fmaxf(S[2][r], S[3][r]));
            mx = fmaxf(mx, __shfl_xor(mx, 1));
            mx = fmaxf(mx, __shfl_xor(mx, 2));
            mx = fmaxf(mx, __shfl_xor(mx, 4));
            mx = fmaxf(mx, __shfl_xor(mx, 8));
            float mnew = fmaxf(m_[r], mx);
            float alpha = __expf(m_[r] - mnew);
            float p0 = __expf(S[0][r] - mnew), p1 = __expf(S[1][r] - mnew);
            float p2 = __expf(S[2][r] - mnew), p3 = __expf(S[3][r] - mnew);
            float ps = p0 + p1 + p2 + p3;
            ps += __shfl_xor(ps, 1); ps += __shfl_xor(ps, 2);
            ps += __shfl_xor(ps, 4); ps += __shfl_xor(ps, 8);
            l_[r] = l_[r] * alpha + ps;
            m_[r] = mnew;
            #pragma unroll
            for (int dn = 0; dn < 4; dn++) o[dn][r] *= alpha;
            int prow = wave * 16 + quad * 4 + r;
            int pl = lane16 >> 3, pc = lane16 & 7;
            sK[prow * 64 + (((0 + pl) ^ (prow & 7)) << 3) + pc] = f2bf(p0);
            sK[prow * 64 + (((2 + pl) ^ (prow & 7)) << 3) + pc] = f2bf(p1);
            sK[prow * 64 + (((4 + pl) ^ (prow & 7)) << 3) + pc] = f2bf(p2);
            sK[prow * 64 + (((6 + pl) ^ (prow & 7)) << 3) + pc] = f2bf(p3);
        }
        // PV: A rows are this wave's own rows (same-wave LDS RAW is in-order safe)
        int Rp = wave * 16 + lane16;
        bf16x8 aP0 = *(const bf16x8*)&sK[Rp * 64 + (((quad    ) ^ (Rp & 7)) << 3)];
        bf16x8 aP1 = *(const bf16x8*)&sK[Rp * 64 + (((quad + 4) ^ (Rp & 7)) << 3)];
        #pragma unroll
        for (int dn = 0; dn < 4; dn++) {
            int R = dn * 16 + lane16;
            bf16x8 b0 = *(const bf16x8*)&sV[R * 64 + (((quad    ) ^ (R & 7)) << 3)];
            bf16x8 b1 = *(const bf16x8*)&sV[R * 64 + (((quad + 4) ^ (R & 7)) << 3)];
            o[dn] = __builtin_amdgcn_mfma_f32_16x16x32_bf16(aP0, b0, o[dn], 0, 0, 0);
            o[dn] = __builtin_amdgcn_mfma_f32_16x16x32_bf16(aP1, b1, o[dn], 0, 0, 0);
        }
    }

    // ---- normalize + store ctx ----
    #pragma unroll
    for (int r = 0; r < 4; r++) {
        float inv = 1.f / l_[r];
        int row = i0 + wave * 16 + quad * 4 + r;
        #pragma unroll
        for (int dn = 0; dn < 4; dn++)
            ctx[(size_t)(b * Sn + row) * Hn + h * 64 + dn * 16 + lane16] = f2bf(o[dn][r] * inv);
    }
}

// ---------------- residual + layernorm (optionally also bf16 copy) ----------------
__global__ __launch_bounds__(256) void k_ln(const float* __restrict__ x1, const float* __restrict__ x2,
                                            const float* __restrict__ g, const float* __restrict__ bb,
                                            float* __restrict__ outf, u16* __restrict__ outh) {
    int row = blockIdx.x, t = threadIdx.x;
    const float* p1 = x1 + (size_t)row * Hn;
    const float* p2 = x2 + (size_t)row * Hn;
    float x[3], s1 = 0.f, s2 = 0.f;
    #pragma unroll
    for (int i = 0; i < 3; i++) {
        int c = t + i * 256;
        float v = p1[c] + p2[c];
        x[i] = v; s1 += v; s2 += v * v;
    }
    for (int off = 32; off; off >>= 1) { s1 += __shfl_xor(s1, off); s2 += __shfl_xor(s2, off); }
    __shared__ float a1[4], a2[4];
    if ((t & 63) == 0) { a1[t >> 6] = s1; a2[t >> 6] = s2; }
    __syncthreads();
    s1 = a1[0] + a1[1] + a1[2] + a1[3];
    s2 = a2[0] + a2[1] + a2[2] + a2[3];
    float mu = s1 * (1.f / 768.f);
    float var = s2 * (1.f / 768.f) - mu * mu;
    float rs = rsqrtf(var + 1e-7f);
    #pragma unroll
    for (int i = 0; i < 3; i++) {
        int c = t + i * 256;
        float y = (x[i] - mu) * rs * g[c] + bb[c];
        outf[(size_t)row * Hn + c] = y;
        if (outh) outh[(size_t)row * Hn + c] = f2bf(y);
    }
}

extern "C" void kernel_launch(void* const* d_in, const int* in_sizes, int n_in,
                              void* d_out, int out_size, void* d_ws, size_t ws_size,
                              hipStream_t stream) {
    const float* hs   = (const float*)d_in[0];
    const float* mask = (const float*)d_in[1];
    const float* pos  = (const float*)d_in[2];
    const float* Wq = (const float*)d_in[3],  *bq = (const float*)d_in[4];
    const float* Wk = (const float*)d_in[5],  *bk = (const float*)d_in[6];
    const float* Wv = (const float*)d_in[7],  *bv = (const float*)d_in[8];
    const float* Wpk = (const float*)d_in[9], *Wpq = (const float*)d_in[10];
    const float* Wo = (const float*)d_in[11], *bo = (const float*)d_in[12];
    const float* g1 = (const float*)d_in[13], *b1ln = (const float*)d_in[14];
    const float* W1 = (const float*)d_in[15], *b1f = (const float*)d_in[16];
    const float* W2 = (const float*)d_in[17], *b2f = (const float*)d_in[18];
    const float* g2 = (const float*)d_in[19], *b2ln = (const float*)d_in[20];
    float* out = (float*)d_out;

    char* w = (char*)d_ws;
    u16*  X16    = (u16*)w;                 w += 12582912;   // [8192,768] bf16
    u16*  pos16  = (u16*)w;                 w += 1572864;    // [1024,768] bf16
    u16*  WqkvT  = (u16*)w;                 w += 3538944;    // [2304,768] bf16
    float* bqkv  = (float*)w;               w += 9216;       // [2304]
    u16*  WoT    = (u16*)w;                 w += 1179648;    // [768,768]
    u16*  W1T    = (u16*)w;                 w += 4718592;    // [3072,768]
    u16*  W2T    = (u16*)w;                 w += 4718592;    // [768,3072]
    u16*  WpkT   = (u16*)w;                 w += 1179648;
    u16*  WpqT   = (u16*)w;                 w += 1179648;    // adjacent to WpkT (merged pos GEMM)
    u16*  posk   = (u16*)w;                 w += 1572864;    // [12][1024][64] bf16 per-head
    u16*  posq   = (u16*)w;                 w += 1572864;    // adjacent to posk (GM_POSH spans both)
    u16*  qkv    = (u16*)w;                 w += 37748736;   // [8192,2304] bf16 (read-only during attn)
    u16*  Vt     = (u16*)w;                 w += 12582912;   // [192,64,512] bf16
    char* big    = w;                       w += 100663296;
    float* attnout = (float*)w;             w += 25165824;   // [8192,768] f32
    // lifetime-disjoint carve-up of `big`:
    u16*  ctx  = (u16*)big;                        // [0, 12.6MB)  written by k_attn
    float* h1f = (float*)(big + 16777216);         // [16MB, 42MB) after Wo+LN1
    u16*  ffn1 = (u16*)(big + 50331648);           // [48MB, 98.6MB)
    u16*  h1h  = X16;                              // X16 dead after qkv GEMM
    float* ffn2 = attnout;                         // attnout dead after LN1

    // prep: converts + fused weight transposes
    k_cvt<<<3072, 256, 0, stream>>>(hs, X16, TOK * Hn);
    k_cvt<<<384, 256, 0, stream>>>(pos, pos16, 1024 * Hn);
    TJobs J;
    J.src[0] = Wq;  J.dst[0] = WqkvT;           J.K[0] = 768;  J.N[0] = 768;
    J.src[1] = Wk;  J.dst[1] = WqkvT + 589824;  J.K[1] = 768;  J.N[1] = 768;
    J.src[2] = Wv;  J.dst[2] = WqkvT + 1179648; J.K[2] = 768;  J.N[2] = 768;
    J.src[3] = Wo;  J.dst[3] = WoT;             J.K[3] = 768;  J.N[3] = 768;
    J.src[4] = Wpk; J.dst[4] = WpkT;            J.K[4] = 768;  J.N[4] = 768;
    J.src[5] = Wpq; J.dst[5] = WpqT;            J.K[5] = 768;  J.N[5] = 768;
    J.src[6] = W1;  J.dst[6] = W1T;             J.K[6] = 768;  J.N[6] = 3072;
    J.src[7] = W2;  J.dst[7] = W2T;             J.K[7] = 3072; J.N[7] = 768;
    J.bstart[0] = 0;
    for (int i = 0; i < 8; i++) J.bstart[i + 1] = J.bstart[i] + (J.N[i] >> 5) * (J.K[i] >> 5);
    k_transpose_all<<<J.bstart[8], dim3(32, 8), 0, stream>>>(J);
    k_pack_bias<<<9, 256, 0, stream>>>(bq, bk, bv, bqkv);

    // projections (merged pos GEMM: N=1536 spans WpkT||WpqT -> posk||posq via GM_POSH)
    k_gemm_t<128><<<dim3(18, 64), 256, 0, stream>>>(X16, WqkvT, bqkv, qkv, TOK, 2304, 768, GM_BF16);
    k_gemm_t<128><<<dim3(12, 8), 256, 0, stream>>>(pos16, WpkT, nullptr, posk, 1024, 1536, 768, GM_POSH);

    // fused attention
    k_vt<<<dim3(8, 192), 256, 0, stream>>>(qkv, Vt);
    k_attn<<<dim3(8, 192), 256, 0, stream>>>(qkv, posk, posq, Vt, mask, ctx);
    k_gemm_t<64><<<dim3(12, 64), 256, 0, stream>>>(ctx, WoT, bo, attnout, TOK, 768, 768, GM_F32);
    k_ln<<<TOK, 256, 0, stream>>>(hs, attnout, g1, b1ln, h1f, h1h);

    // FFN
    k_gemm_t<128><<<dim3(24, 64), 256, 0, stream>>>(h1h, W1T, b1f, ffn1, TOK, 3072, 768, GM_GELU_BF16);
    k_gemm_t<64><<<dim3(12, 64), 256, 0, stream>>>(ffn1, W2T, b2f, ffn2, TOK, 768, 3072, GM_F32);
    k_ln<<<TOK, 256, 0, stream>>>(h1f, ffn2, g2, b2ln, out, nullptr);
}

// Round 9
// 529.725 us; speedup vs baseline: 1.0412x; 1.0412x over previous
//
#include <hip/hip_runtime.h>
#include <math.h>

#define Bn 16
#define Sn 512
#define Hn 768
#define NHn 12
#define DHn 64
#define In 3072
#define TOK (Bn*Sn)

typedef unsigned short u16;
typedef short bf16x8 __attribute__((ext_vector_type(8)));
typedef short bf16x4 __attribute__((ext_vector_type(4)));
typedef float f32x4 __attribute__((ext_vector_type(4)));

__device__ __forceinline__ u16 f2bf(float x) {
    union { float f; unsigned u; } v; v.f = x;
    unsigned r = v.u + 0x7FFF + ((v.u >> 16) & 1);
    return (u16)(r >> 16);
}
__device__ __forceinline__ float bf2f(u16 u) {
    union { unsigned u; float f; } v; v.u = ((unsigned)u) << 16; return v.f;
}

// async global->LDS DMA, 16 B/lane; dest = wave-uniform base + lane*16
__device__ __forceinline__ void gl_lds16(const void* g, void* s) {
    __builtin_amdgcn_global_load_lds((const __attribute__((address_space(1))) void*)g,
                                     (__attribute__((address_space(3))) void*)s, 16, 0, 0);
}

// ---------------- elementwise f32 -> bf16 ----------------
__global__ __launch_bounds__(256) void k_cvt(const float* __restrict__ in, u16* __restrict__ out, int n) {
    int i = (blockIdx.x * 256 + threadIdx.x) * 8;
    if (i + 8 > n) return;
    float4 a = *(const float4*)(in + i);
    float4 b = *(const float4*)(in + i + 4);
    bf16x8 o;
    o[0] = (short)f2bf(a.x); o[1] = (short)f2bf(a.y); o[2] = (short)f2bf(a.z); o[3] = (short)f2bf(a.w);
    o[4] = (short)f2bf(b.x); o[5] = (short)f2bf(b.y); o[6] = (short)f2bf(b.z); o[7] = (short)f2bf(b.w);
    *(bf16x8*)(out + i) = o;
}

// ---------------- fused weight transposes: f32[K,N] -> bf16[N,K], 8 jobs ----------------
struct TJobs {
    const float* src[8];
    u16* dst[8];
    int K[8];
    int N[8];
    int bstart[9];
};

__global__ __launch_bounds__(256) void k_transpose_all(TJobs J) {
    __shared__ float tile[32][33];
    int bid = blockIdx.x;
    int ji = 0;
    #pragma unroll
    for (int t = 0; t < 8; t++) if (bid >= J.bstart[t + 1]) ji = t + 1;
    const float* W = J.src[ji];
    u16* Wt = J.dst[ji];
    int K = J.K[ji], N = J.N[ji];
    int local = bid - J.bstart[ji];
    int nbx = N >> 5;
    int bx = local % nbx, by = local / nbx;
    int n0 = bx * 32, k0 = by * 32;
    int tx = threadIdx.x, ty = threadIdx.y;  // (32,8)
    #pragma unroll
    for (int i = 0; i < 32; i += 8)
        tile[ty + i][tx] = W[(size_t)(k0 + ty + i) * N + n0 + tx];
    __syncthreads();
    #pragma unroll
    for (int i = 0; i < 32; i += 8)
        Wt[(size_t)(n0 + ty + i) * K + k0 + tx] = f2bf(tile[tx][ty + i]);
}

__global__ __launch_bounds__(256) void k_pack_bias(const float* __restrict__ bq, const float* __restrict__ bk,
                                                   const float* __restrict__ bv, float* __restrict__ bqkv) {
    int i = blockIdx.x * 256 + threadIdx.x;
    if (i < 2304) bqkv[i] = (i < 768) ? bq[i] : (i < 1536 ? bk[i - 768] : bv[i - 1536]);
}

// ---------------- bf16 MFMA GEMM: BK=64, global_load_lds, XOR swizzle, XCD-affinity remap ----------------
#define GM_BF16 0
#define GM_F32 1
#define GM_GELU_BF16 2
#define GM_POSH 3   // write bf16 to [h][r][d]: h=col>>6, d=col&63, idx=h*65536+row*64+d

template<int NT>
__global__ __launch_bounds__(256) void k_gemm_t(const u16* __restrict__ A, const u16* __restrict__ Bt,
                                                const float* __restrict__ bias, void* __restrict__ Cout,
                                                int M, int N, int K, int mode) {
    constexpr int TN = NT / 32;
    __shared__ __align__(16) u16 sA[128 * 64];
    __shared__ __align__(16) u16 sB[NT * 64];
    int tid = threadIdx.x;
    int wave = tid >> 6, lane = tid & 63;
    int lane16 = lane & 15, quad = lane >> 4;

    int nb = gridDim.x;
    int flat = blockIdx.y * nb + blockIdx.x;
    int c = flat & 7, g = flat >> 3;
    int mt = c + 8 * (g / nb), nt = g % nb;   // requires gridDim.y % 8 == 0
    int m0 = mt * 128, n0 = nt * NT;

    int wm = (wave >> 1) * 64;
    int wn = (wave & 1) * (NT / 2);
    f32x4 acc[4][TN] = {};

    int r_st = lane >> 3;
    int c8p = lane & 7;

    for (int k0 = 0; k0 < K; k0 += 64) {
        __syncthreads();
        #pragma unroll
        for (int I = 0; I < 4; I++) {
            int Ii = wave + I * 4;
            int r = Ii * 8 + r_st;
            int c8 = c8p ^ (r & 7);
            gl_lds16(&A[(size_t)(m0 + r) * K + k0 + c8 * 8], &sA[Ii * 512]);
        }
        #pragma unroll
        for (int I = 0; I < NT / 32; I++) {
            int Ii = wave + I * 4;
            int r = Ii * 8 + r_st;
            int c8 = c8p ^ (r & 7);
            gl_lds16(&Bt[(size_t)(n0 + r) * K + k0 + c8 * 8], &sB[Ii * 512]);
        }
        __syncthreads();
        #pragma unroll
        for (int h = 0; h < 2; h++) {
            bf16x8 af[4], bfr[TN];
            #pragma unroll
            for (int t = 0; t < 4; t++) {
                int R = wm + t * 16 + lane16;
                af[t] = *(const bf16x8*)&sA[R * 64 + (((4 * h + quad) ^ (R & 7)) << 3)];
            }
            #pragma unroll
            for (int t = 0; t < TN; t++) {
                int R = wn + t * 16 + lane16;
                bfr[t] = *(const bf16x8*)&sB[R * 64 + (((4 * h + quad) ^ (R & 7)) << 3)];
            }
            #pragma unroll
            for (int tm = 0; tm < 4; tm++)
                #pragma unroll
                for (int tn = 0; tn < TN; tn++)
                    acc[tm][tn] = __builtin_amdgcn_mfma_f32_16x16x32_bf16(af[tm], bfr[tn], acc[tm][tn], 0, 0, 0);
        }
    }

    float* Cf = (float*)Cout;
    u16* Ch = (u16*)Cout;
    #pragma unroll
    for (int tm = 0; tm < 4; tm++) {
        #pragma unroll
        for (int tn = 0; tn < TN; tn++) {
            int col = n0 + wn + tn * 16 + lane16;
            float bv_ = bias ? bias[col] : 0.f;
            #pragma unroll
            for (int r = 0; r < 4; r++) {
                int row = m0 + wm + tm * 16 + quad * 4 + r;
                float v = acc[tm][tn][r] + bv_;
                if (mode == GM_GELU_BF16) {
                    v = 0.5f * v * (1.f + erff(v * 0.70710678118654752f));
                    Ch[(size_t)row * N + col] = f2bf(v);
                } else if (mode == GM_BF16) {
                    Ch[(size_t)row * N + col] = f2bf(v);
                } else if (mode == GM_POSH) {
                    Ch[(((size_t)col >> 6) << 16) + ((size_t)row << 6) + (col & 63)] = f2bf(v);
                } else {
                    Cf[(size_t)row * N + col] = v;
                }
            }
        }
    }
}

// ---------------- V transpose: qkv[tok, 1536+h*64+d] -> Vt[(b,h), d, j] ----------------
__global__ __launch_bounds__(256) void k_vt(const u16* __restrict__ qkv, u16* __restrict__ Vt) {
    __shared__ u16 s[64][72];
    int z = blockIdx.y;  // b*12+h
    int j0 = blockIdx.x * 64;
    int b = z / NHn, h = z % NHn;
    int t = threadIdx.x;
    for (int e = t; e < 4096; e += 256) {
        int j = e >> 6, d = e & 63;
        s[j][d] = qkv[(size_t)(b * Sn + j0 + j) * 2304 + 1536 + h * 64 + d];
    }
    __syncthreads();
    for (int e = t; e < 4096; e += 256) {
        int d = e >> 6, jj = e & 63;
        Vt[((size_t)z * 64 + d) * Sn + j0 + jj] = s[jj][d];
    }
}

// ---------------- fused disentangled attention, XCD-affinity with TEMPORAL z-grouping ----------------
// flat = y*8+x; xcd=flat&7; g=flat>>3; z = xcd*24 + (g>>3); i0 = (g&7)*64
// -> the 8 i-tiles of one z are CONSECUTIVE blocks on ONE XCD: K/V panel fetched once
//    into that XCD's L2 and consumed while hot; each XCD visits each head h twice,
//    keeping the 3 MB pos tables L2-resident. (R8's g%24 ordering cycled 24 z's and
//    thrashed - FETCH 282 MB.)
// LDS (u16 idx): sK [0,4096) (Q stage at start, P surface later), sV [4096,8192),
// sPK [8192,16384), sPQ [16384,24576); scatter alias s1 [8192,16896), s2 [16896,25600).
__global__ __launch_bounds__(256, 3) void k_attn(const u16* __restrict__ qkv, const u16* __restrict__ poskR,
                                                 const u16* __restrict__ posqR, const u16* __restrict__ Vt,
                                                 const float* __restrict__ mask, u16* __restrict__ ctx) {
    __shared__ __align__(16) u16 smem[25600];
    u16* sK = smem;
    u16* sV = smem + 4096;
    u16* sPK = smem + 8192;
    u16* s1 = smem + 8192;
    u16* s2 = smem + 16896;

    int flat = blockIdx.y * gridDim.x + blockIdx.x;   // grid (8,192)
    int xcd = flat & 7, g = flat >> 3;                // g in [0,192)
    int z = xcd * 24 + (g >> 3);
    int i0 = (g & 7) * 64;
    int b = z / NHn, h = z % NHn;
    int tid = threadIdx.x, wave = tid >> 6, lane = tid & 63;
    int lane16 = lane & 15, quad = lane >> 4;
    int lr = lane >> 3, lc8 = lane & 7;
    int c8v = (lc8 ^ lr) << 3;   // lane-const swizzled chunk offset (r&7 == lr for all chunks)

    // ---- stage Q once (into sK), read A-fragments ----
    #pragma unroll
    for (int I = 0; I < 2; I++) {
        int CI = wave * 2 + I;
        int r = CI * 8 + lr;
        gl_lds16(&qkv[(size_t)(b * Sn + i0 + r) * 2304 + h * 64 + c8v], &sK[CI * 512]);
    }
    __syncthreads();
    int Rq = wave * 16 + lane16;
    bf16x8 aq0 = *(const bf16x8*)&sK[Rq * 64 + (((quad    ) ^ (Rq & 7)) << 3)];
    bf16x8 aq1 = *(const bf16x8*)&sK[Rq * 64 + (((quad + 4) ^ (Rq & 7)) << 3)];

    // ---- hoisted staging pointers ----
    const u16* kp0 = qkv + (size_t)(b * Sn + wave * 8 + lr) * 2304 + 768 + h * 64 + c8v;
    const u16* kp1 = qkv + (size_t)(b * Sn + (4 + wave) * 8 + lr) * 2304 + 768 + h * 64 + c8v;
    const u16* vp0 = Vt + ((size_t)z * 64 + wave * 8 + lr) * Sn + c8v;
    const u16* vp1 = Vt + ((size_t)z * 64 + (4 + wave) * 8 + lr) * Sn + c8v;
    const u16* pkb = poskR + (size_t)h * 65536 + c8v;
    const u16* pqb = posqR + (size_t)h * 65536 + c8v;
    int rl0 = wave * 8 + lr;   // pos row lane-term for chunk group q: rl0 + 32q

    f32x4 o[4] = {};
    float m_[4] = {-1e30f, -1e30f, -1e30f, -1e30f};
    float l_[4] = {};
    const float scale = 0.07216878364870323f;  // 1/sqrt(3*64)

    for (int jt = 0; jt < 8; jt++) {
        int j0 = jt * 64;
        int r0pk = i0 - j0 + 449, r0pq = j0 - i0 + 449;
        __syncthreads();  // prior iter's P/sV/s1/s2 uses complete before restage
        // ---- stage K(8) V(8) PK(16) PQ(16) 1KB-chunks, 12 DMA per wave ----
        gl_lds16(kp0, &smem[(wave    ) * 512]);  kp0 += 64 * 2304;
        gl_lds16(kp1, &smem[(4 + wave) * 512]);  kp1 += 64 * 2304;
        gl_lds16(vp0, &smem[(8 + wave) * 512]);  vp0 += 64;
        gl_lds16(vp1, &smem[(12 + wave) * 512]); vp1 += 64;
        #pragma unroll
        for (int q = 0; q < 4; q++) {
            int rl = rl0 + 32 * q;
            int rowk = min(r0pk + rl, 1023);
            int rowq = min(r0pq + rl, 1023);
            gl_lds16(pkb + ((size_t)rowk << 6), &smem[(16 + 4 * q + wave) * 512]);
            gl_lds16(pqb + ((size_t)rowq << 6), &smem[(32 + 4 * q + wave) * 512]);
        }
        float mv[4];
        #pragma unroll
        for (int tn = 0; tn < 4; tn++) mv[tn] = mask[(size_t)b * Sn + j0 + tn * 16 + lane16];
        __syncthreads();  // DMA drain + barrier

        // ---- MFMA phase ----
        bf16x8 ak0 = *(const bf16x8*)&sK[Rq * 64 + (((quad    ) ^ (Rq & 7)) << 3)];
        bf16x8 ak1 = *(const bf16x8*)&sK[Rq * 64 + (((quad + 4) ^ (Rq & 7)) << 3)];
        f32x4 cc[4];
        #pragma unroll
        for (int tn = 0; tn < 4; tn++) {
            int R = tn * 16 + lane16;
            bf16x8 b0 = *(const bf16x8*)&sK[R * 64 + (((quad    ) ^ (R & 7)) << 3)];
            bf16x8 b1 = *(const bf16x8*)&sK[R * 64 + (((quad + 4) ^ (R & 7)) << 3)];
            f32x4 x = {};
            x = __builtin_amdgcn_mfma_f32_16x16x32_bf16(aq0, b0, x, 0, 0, 0);
            x = __builtin_amdgcn_mfma_f32_16x16x32_bf16(aq1, b1, x, 0, 0, 0);
            cc[tn] = x;
        }
        f32x4 a1[8], a2[8];
        #pragma unroll
        for (int tr = 0; tr < 8; tr++) {
            int R = tr * 16 + lane16;
            bf16x8 b0 = *(const bf16x8*)&sPK[R * 64 + (((quad    ) ^ (R & 7)) << 3)];
            bf16x8 b1 = *(const bf16x8*)&sPK[R * 64 + (((quad + 4) ^ (R & 7)) << 3)];
            bf16x8 c0 = *(const bf16x8*)&sPK[8192 + R * 64 + (((quad    ) ^ (R & 7)) << 3)];
            bf16x8 c1 = *(const bf16x8*)&sPK[8192 + R * 64 + (((quad + 4) ^ (R & 7)) << 3)];
            f32x4 x = {}, y = {};
            x = __builtin_amdgcn_mfma_f32_16x16x32_bf16(aq0, b0, x, 0, 0, 0);
            x = __builtin_amdgcn_mfma_f32_16x16x32_bf16(aq1, b1, x, 0, 0, 0);
            y = __builtin_amdgcn_mfma_f32_16x16x32_bf16(ak0, c0, y, 0, 0, 0);
            y = __builtin_amdgcn_mfma_f32_16x16x32_bf16(ak1, c1, y, 0, 0, 0);
            a1[tr] = x; a2[tr] = y;
        }
        __syncthreads();  // pos-window reads done; sPK/sPQ become s1/s2

        // ---- diagonal scatter (bf16, per-wave disjoint columns) ----
        int sw = wave * 16 + quad * 4;
        #pragma unroll
        for (int tr = 0; tr < 8; tr++) {
            bf16x4 oo, pp;
            oo[0] = (short)f2bf(a1[tr][0]); oo[1] = (short)f2bf(a1[tr][1]);
            oo[2] = (short)f2bf(a1[tr][2]); oo[3] = (short)f2bf(a1[tr][3]);
            pp[0] = (short)f2bf(a2[tr][0]); pp[1] = (short)f2bf(a2[tr][1]);
            pp[2] = (short)f2bf(a2[tr][2]); pp[3] = (short)f2bf(a2[tr][3]);
            *(bf16x4*)&s1[(tr * 16 + lane16) * 68 + sw] = oo;
            *(bf16x4*)&s2[(tr * 16 + lane16) * 68 + sw] = pp;
        }
        __syncthreads();

        // ---- gather + online softmax + P write (into dead sK, swizzled) + PV ----
        float S[4][4];
        #pragma unroll
        for (int tn = 0; tn < 4; tn++) {
            int jL = tn * 16 + lane16;
            #pragma unroll
            for (int r = 0; r < 4; r++) {
                int iL = wave * 16 + quad * 4 + r;
                float v = cc[tn][r] + bf2f(s1[(iL - jL + 63) * 68 + iL])
                                    + bf2f(s2[(jL - iL + 63) * 68 + jL]);
                v *= scale;
                S[tn][r] = (mv[tn] > 0.f) ? v : -1e9f;
            }
        }
        #pragma unroll
        for (int r = 0; r < 4; r++) {
            float mx = fmaxf(fmaxf(S[0][r], S[1][r]), fmaxf(S[2][r], S[3][r]));
            mx = fmaxf(mx, __shfl_xor(mx, 1));
            mx = fmaxf(mx, __shfl_xor(mx, 2));
            mx = fmaxf(mx, __shfl_xor(mx, 4));
            mx = fmaxf(mx, __shfl_xor(mx, 8));
            float mnew = fmaxf(m_[r], mx);
            float alpha = __expf(m_[r] - mnew);
            float p0 = __expf(S[0][r] - mnew), p1 = __expf(S[1][r] - mnew);
            float p2 = __expf(S[2][r] - mnew), p3 = __expf(S[3][r] - mnew);
            float ps = p0 + p1 + p2 + p3;
            ps += __shfl_xor(ps, 1); ps += __shfl_xor(ps, 2);
            ps += __shfl_xor(ps, 4); ps += __shfl_xor(ps, 8);
            l_[r] = l_[r] * alpha + ps;
            m_[r] = mnew;
            #pragma unroll
            for (int dn = 0; dn < 4; dn++) o[dn][r] *= alpha;
            int prow = wave * 16 + quad * 4 + r;
            int pl = lane16 >> 3, pc = lane16 & 7;
            sK[prow * 64 + (((0 + pl) ^ (prow & 7)) << 3) + pc] = f2bf(p0);
            sK[prow * 64 + (((2 + pl) ^ (prow & 7)) << 3) + pc] = f2bf(p1);
            sK[prow * 64 + (((4 + pl) ^ (prow & 7)) << 3) + pc] = f2bf(p2);
            sK[prow * 64 + (((6 + pl) ^ (prow & 7)) << 3) + pc] = f2bf(p3);
        }
        // PV: A rows are this wave's own rows (same-wave LDS RAW is in-order safe)
        int Rp = wave * 16 + lane16;
        bf16x8 aP0 = *(const bf16x8*)&sK[Rp * 64 + (((quad    ) ^ (Rp & 7)) << 3)];
        bf16x8 aP1 = *(const bf16x8*)&sK[Rp * 64 + (((quad + 4) ^ (Rp & 7)) << 3)];
        #pragma unroll
        for (int dn = 0; dn < 4; dn++) {
            int R = dn * 16 + lane16;
            bf16x8 b0 = *(const bf16x8*)&sV[R * 64 + (((quad    ) ^ (R & 7)) << 3)];
            bf16x8 b1 = *(const bf16x8*)&sV[R * 64 + (((quad + 4) ^ (R & 7)) << 3)];
            o[dn] = __builtin_amdgcn_mfma_f32_16x16x32_bf16(aP0, b0, o[dn], 0, 0, 0);
            o[dn] = __builtin_amdgcn_mfma_f32_16x16x32_bf16(aP1, b1, o[dn], 0, 0, 0);
        }
    }

    // ---- normalize + store ctx ----
    #pragma unroll
    for (int r = 0; r < 4; r++) {
        float inv = 1.f / l_[r];
        int row = i0 + wave * 16 + quad * 4 + r;
        #pragma unroll
        for (int dn = 0; dn < 4; dn++)
            ctx[(size_t)(b * Sn + row) * Hn + h * 64 + dn * 16 + lane16] = f2bf(o[dn][r] * inv);
    }
}

// ---------------- residual + layernorm (optionally also bf16 copy) ----------------
__global__ __launch_bounds__(256) void k_ln(const float* __restrict__ x1, const float* __restrict__ x2,
                                            const float* __restrict__ g, const float* __restrict__ bb,
                                            float* __restrict__ outf, u16* __restrict__ outh) {
    int row = blockIdx.x, t = threadIdx.x;
    const float* p1 = x1 + (size_t)row * Hn;
    const float* p2 = x2 + (size_t)row * Hn;
    float x[3], s1 = 0.f, s2 = 0.f;
    #pragma unroll
    for (int i = 0; i < 3; i++) {
        int c = t + i * 256;
        float v = p1[c] + p2[c];
        x[i] = v; s1 += v; s2 += v * v;
    }
    for (int off = 32; off; off >>= 1) { s1 += __shfl_xor(s1, off); s2 += __shfl_xor(s2, off); }
    __shared__ float a1[4], a2[4];
    if ((t & 63) == 0) { a1[t >> 6] = s1; a2[t >> 6] = s2; }
    __syncthreads();
    s1 = a1[0] + a1[1] + a1[2] + a1[3];
    s2 = a2[0] + a2[1] + a2[2] + a2[3];
    float mu = s1 * (1.f / 768.f);
    float var = s2 * (1.f / 768.f) - mu * mu;
    float rs = rsqrtf(var + 1e-7f);
    #pragma unroll
    for (int i = 0; i < 3; i++) {
        int c = t + i * 256;
        float y = (x[i] - mu) * rs * g[c] + bb[c];
        outf[(size_t)row * Hn + c] = y;
        if (outh) outh[(size_t)row * Hn + c] = f2bf(y);
    }
}

extern "C" void kernel_launch(void* const* d_in, const int* in_sizes, int n_in,
                              void* d_out, int out_size, void* d_ws, size_t ws_size,
                              hipStream_t stream) {
    const float* hs   = (const float*)d_in[0];
    const float* mask = (const float*)d_in[1];
    const float* pos  = (const float*)d_in[2];
    const float* Wq = (const float*)d_in[3],  *bq = (const float*)d_in[4];
    const float* Wk = (const float*)d_in[5],  *bk = (const float*)d_in[6];
    const float* Wv = (const float*)d_in[7],  *bv = (const float*)d_in[8];
    const float* Wpk = (const float*)d_in[9], *Wpq = (const float*)d_in[10];
    const float* Wo = (const float*)d_in[11], *bo = (const float*)d_in[12];
    const float* g1 = (const float*)d_in[13], *b1ln = (const float*)d_in[14];
    const float* W1 = (const float*)d_in[15], *b1f = (const float*)d_in[16];
    const float* W2 = (const float*)d_in[17], *b2f = (const float*)d_in[18];
    const float* g2 = (const float*)d_in[19], *b2ln = (const float*)d_in[20];
    float* out = (float*)d_out;

    char* w = (char*)d_ws;
    u16*  X16    = (u16*)w;                 w += 12582912;   // [8192,768] bf16
    u16*  pos16  = (u16*)w;                 w += 1572864;    // [1024,768] bf16
    u16*  WqkvT  = (u16*)w;                 w += 3538944;    // [2304,768] bf16
    float* bqkv  = (float*)w;               w += 9216;       // [2304]
    u16*  WoT    = (u16*)w;                 w += 1179648;    // [768,768]
    u16*  W1T    = (u16*)w;                 w += 4718592;    // [3072,768]
    u16*  W2T    = (u16*)w;                 w += 4718592;    // [768,3072]
    u16*  WpkT   = (u16*)w;                 w += 1179648;
    u16*  WpqT   = (u16*)w;                 w += 1179648;    // adjacent to WpkT (merged pos GEMM)
    u16*  posk   = (u16*)w;                 w += 1572864;    // [12][1024][64] bf16 per-head
    u16*  posq   = (u16*)w;                 w += 1572864;    // adjacent to posk (GM_POSH spans both)
    u16*  qkv    = (u16*)w;                 w += 37748736;   // [8192,2304] bf16 (read-only during attn)
    u16*  Vt     = (u16*)w;                 w += 12582912;   // [192,64,512] bf16
    char* big    = w;                       w += 100663296;
    float* attnout = (float*)w;             w += 25165824;   // [8192,768] f32
    // lifetime-disjoint carve-up of `big`:
    u16*  ctx  = (u16*)big;                        // [0, 12.6MB)  written by k_attn
    float* h1f = (float*)(big + 16777216);         // [16MB, 42MB) after Wo+LN1
    u16*  ffn1 = (u16*)(big + 50331648);           // [48MB, 98.6MB)
    u16*  h1h  = X16;                              // X16 dead after qkv GEMM
    float* ffn2 = attnout;                         // attnout dead after LN1

    // prep: converts + fused weight transposes
    k_cvt<<<3072, 256, 0, stream>>>(hs, X16, TOK * Hn);
    k_cvt<<<384, 256, 0, stream>>>(pos, pos16, 1024 * Hn);
    TJobs J;
    J.src[0] = Wq;  J.dst[0] = WqkvT;           J.K[0] = 768;  J.N[0] = 768;
    J.src[1] = Wk;  J.dst[1] = WqkvT + 589824;  J.K[1] = 768;  J.N[1] = 768;
    J.src[2] = Wv;  J.dst[2] = WqkvT + 1179648; J.K[2] = 768;  J.N[2] = 768;
    J.src[3] = Wo;  J.dst[3] = WoT;             J.K[3] = 768;  J.N[3] = 768;
    J.src[4] = Wpk; J.dst[4] = WpkT;            J.K[4] = 768;  J.N[4] = 768;
    J.src[5] = Wpq; J.dst[5] = WpqT;            J.K[5] = 768;  J.N[5] = 768;
    J.src[6] = W1;  J.dst[6] = W1T;             J.K[6] = 768;  J.N[6] = 3072;
    J.src[7] = W2;  J.dst[7] = W2T;             J.K[7] = 3072; J.N[7] = 768;
    J.bstart[0] = 0;
    for (int i = 0; i < 8; i++) J.bstart[i + 1] = J.bstart[i] + (J.N[i] >> 5) * (J.K[i] >> 5);
    k_transpose_all<<<J.bstart[8], dim3(32, 8), 0, stream>>>(J);
    k_pack_bias<<<9, 256, 0, stream>>>(bq, bk, bv, bqkv);

    // projections (merged pos GEMM: N=1536 spans WpkT||WpqT -> posk||posq via GM_POSH)
    k_gemm_t<128><<<dim3(18, 64), 256, 0, stream>>>(X16, WqkvT, bqkv, qkv, TOK, 2304, 768, GM_BF16);
    k_gemm_t<128><<<dim3(12, 8), 256, 0, stream>>>(pos16, WpkT, nullptr, posk, 1024, 1536, 768, GM_POSH);

    // fused attention
    k_vt<<<dim3(8, 192), 256, 0, stream>>>(qkv, Vt);
    k_attn<<<dim3(8, 192), 256, 0, stream>>>(qkv, posk, posq, Vt, mask, ctx);
    k_gemm_t<64><<<dim3(12, 64), 256, 0, stream>>>(ctx, WoT, bo, attnout, TOK, 768, 768, GM_F32);
    k_ln<<<TOK, 256, 0, stream>>>(hs, attnout, g1, b1ln, h1f, h1h);

    // FFN
    k_gemm_t<128><<<dim3(24, 64), 256, 0, stream>>>(h1h, W1T, b1f, ffn1, TOK, 3072, 768, GM_GELU_BF16);
    k_gemm_t<64><<<dim3(12, 64), 256, 0, stream>>>(ffn1, W2T, b2f, ffn2, TOK, 768, 3072, GM_F32);
    k_ln<<<TOK, 256, 0, stream>>>(h1f, ffn2, g2, b2ln, out, nullptr);
}